// Round 1
// baseline (1067.520 us; speedup 1.0000x reference)
//
#include <hip/hip_runtime.h>

#define D_FEAT 128

__global__ void deg_kernel(const int* __restrict__ h, float* __restrict__ deg, int E) {
    int i = blockIdx.x * blockDim.x + threadIdx.x;
    if (i < E) atomicAdd(&deg[h[i]], 1.0f);
}

// 32 threads per edge; thread j handles float4 chunk j of the 128-feature row.
__global__ void scatter_kernel(const float* __restrict__ x,
                               const int* __restrict__ h,
                               const int* __restrict__ t,
                               const float* __restrict__ deg,
                               float* __restrict__ out, int E) {
    long long tid = (long long)blockIdx.x * blockDim.x + threadIdx.x;
    int e = (int)(tid >> 5);
    int j = (int)(tid & 31);
    if (e >= E) return;
    int hs = h[e];
    int ts = t[e];
    float nr = rsqrtf(deg[hs]) * rsqrtf(deg[ts]);
    const float4* xs = reinterpret_cast<const float4*>(x + (size_t)hs * D_FEAT);
    float4 v = xs[j];
    float* o = out + (size_t)ts * D_FEAT + j * 4;
    atomicAdd(o + 0, nr * v.x);
    atomicAdd(o + 1, nr * v.y);
    atomicAdd(o + 2, nr * v.z);
    atomicAdd(o + 3, nr * v.w);
}

__global__ void relu_kernel(float* __restrict__ out, int n4) {
    int i = blockIdx.x * blockDim.x + threadIdx.x;
    if (i < n4) {
        float4* p = reinterpret_cast<float4*>(out);
        float4 v = p[i];
        v.x = fmaxf(v.x, 0.0f);
        v.y = fmaxf(v.y, 0.0f);
        v.z = fmaxf(v.z, 0.0f);
        v.w = fmaxf(v.w, 0.0f);
        p[i] = v;
    }
}

extern "C" void kernel_launch(void* const* d_in, const int* in_sizes, int n_in,
                              void* d_out, int out_size, void* d_ws, size_t ws_size,
                              hipStream_t stream) {
    const float* x = (const float*)d_in[0];
    const int*   h = (const int*)d_in[1];
    const int*   t = (const int*)d_in[2];
    float* out = (float*)d_out;

    int N = in_sizes[0] / D_FEAT;   // 100000
    int E = in_sizes[1];            // 600000

    float* deg = (float*)d_ws;      // N floats (400 KB)

    // Zero output accumulator and degree histogram (async, graph-capturable).
    hipMemsetAsync(d_out, 0, (size_t)out_size * sizeof(float), stream);
    hipMemsetAsync(deg, 0, (size_t)N * sizeof(float), stream);

    // 1) degree histogram
    deg_kernel<<<(E + 255) / 256, 256, 0, stream>>>(h, deg, E);

    // 2) normalized scatter-add: 32 threads/edge
    long long total = (long long)E * 32;
    int blocks = (int)((total + 255) / 256);
    scatter_kernel<<<blocks, 256, 0, stream>>>(x, h, t, deg, out, E);

    // 3) ReLU in-place (float4)
    int n4 = out_size / 4;
    relu_kernel<<<(n4 + 255) / 256, 256, 0, stream>>>(out, n4);
}

// Round 2
// 150.378 us; speedup vs baseline: 7.0989x; 7.0989x over previous
//
#include <hip/hip_runtime.h>

#define D_FEAT 128
#define SCAN_BLK 1024

// Histogram of sources (for deg/norm) and targets (for CSR row counts).
__global__ void hist_kernel(const int* __restrict__ h, const int* __restrict__ t,
                            int* __restrict__ hcnt, int* __restrict__ tcnt, int E) {
    int i = blockIdx.x * blockDim.x + threadIdx.x;
    if (i < E) {
        atomicAdd(&hcnt[h[i]], 1);
        atomicAdd(&tcnt[t[i]], 1);
    }
}

// Per-block exclusive scan (Hillis-Steele in LDS), emits block sums.
__global__ void scan_block_kernel(const int* __restrict__ in, int* __restrict__ out,
                                  int* __restrict__ bsum, int n) {
    __shared__ int tmp[SCAN_BLK];
    int i = blockIdx.x * SCAN_BLK + threadIdx.x;
    int v = (i < n) ? in[i] : 0;
    tmp[threadIdx.x] = v;
    __syncthreads();
    for (int off = 1; off < SCAN_BLK; off <<= 1) {
        int w = (threadIdx.x >= off) ? tmp[threadIdx.x - off] : 0;
        __syncthreads();
        tmp[threadIdx.x] += w;
        __syncthreads();
    }
    if (i < n) out[i] = tmp[threadIdx.x] - v;  // exclusive
    if (threadIdx.x == SCAN_BLK - 1) bsum[blockIdx.x] = tmp[threadIdx.x];
}

// Exclusive scan of the (<=256) block sums in a single block.
__global__ void scan_small_kernel(int* __restrict__ bsum, int nb) {
    __shared__ int tmp[256];
    int v = (threadIdx.x < nb) ? bsum[threadIdx.x] : 0;
    tmp[threadIdx.x] = v;
    __syncthreads();
    for (int off = 1; off < 256; off <<= 1) {
        int w = (threadIdx.x >= off) ? tmp[threadIdx.x - off] : 0;
        __syncthreads();
        tmp[threadIdx.x] += w;
        __syncthreads();
    }
    if (threadIdx.x < nb) bsum[threadIdx.x] = tmp[threadIdx.x] - v;
}

// row_ptr finalize (+block offsets), cursor copy, dis = deg^-1/2.
__global__ void finalize_kernel(int* __restrict__ row_ptr, const int* __restrict__ bsum,
                                int* __restrict__ cursor, const int* __restrict__ hcnt,
                                float* __restrict__ dis, int n, int E) {
    int i = blockIdx.x * blockDim.x + threadIdx.x;
    if (i < n) {
        int r = row_ptr[i] + bsum[i / SCAN_BLK];
        row_ptr[i] = r;
        cursor[i] = r;
        dis[i] = rsqrtf((float)hcnt[i]);
    }
    if (i == 0) row_ptr[n] = E;
}

// Bucket edges by target: edge_src[pos] = h[e].
__global__ void place_kernel(const int* __restrict__ h, const int* __restrict__ t,
                             int* __restrict__ cursor, int* __restrict__ edge_src, int E) {
    int i = blockIdx.x * blockDim.x + threadIdx.x;
    if (i < E) {
        int pos = atomicAdd(&cursor[t[i]], 1);
        edge_src[pos] = h[i];
    }
}

// One 32-lane group per node; lane j owns float4 chunk j of the 128-feat row.
// Register accumulation, single coalesced write, fused ReLU. No atomics.
__global__ void gather_kernel(const float* __restrict__ x, const int* __restrict__ row_ptr,
                              const int* __restrict__ edge_src, const float* __restrict__ dis,
                              float* __restrict__ out, int n) {
    int gid = blockIdx.x * blockDim.x + threadIdx.x;
    int node = gid >> 5;
    int j = gid & 31;
    if (node >= n) return;
    int beg = row_ptr[node];
    int end = row_ptr[node + 1];
    float dd = dis[node];
    const float4* x4 = reinterpret_cast<const float4*>(x);
    float4 acc = make_float4(0.f, 0.f, 0.f, 0.f);
    for (int k = beg; k < end; ++k) {
        int s = edge_src[k];          // lane-uniform (broadcast)
        float nr = dd * dis[s];       // lane-uniform (broadcast)
        float4 v = x4[(size_t)s * 32 + j];  // coalesced 512B row read
        acc.x = fmaf(nr, v.x, acc.x);
        acc.y = fmaf(nr, v.y, acc.y);
        acc.z = fmaf(nr, v.z, acc.z);
        acc.w = fmaf(nr, v.w, acc.w);
    }
    float4 r;
    r.x = fmaxf(acc.x, 0.f);
    r.y = fmaxf(acc.y, 0.f);
    r.z = fmaxf(acc.z, 0.f);
    r.w = fmaxf(acc.w, 0.f);
    reinterpret_cast<float4*>(out)[(size_t)node * 32 + j] = r;
}

extern "C" void kernel_launch(void* const* d_in, const int* in_sizes, int n_in,
                              void* d_out, int out_size, void* d_ws, size_t ws_size,
                              hipStream_t stream) {
    const float* x = (const float*)d_in[0];
    const int*   h = (const int*)d_in[1];
    const int*   t = (const int*)d_in[2];
    float* out = (float*)d_out;

    int N = in_sizes[0] / D_FEAT;   // 100000
    int E = in_sizes[1];            // 600000
    int nb = (N + SCAN_BLK - 1) / SCAN_BLK;  // 98 (<=256 assumed)

    // Workspace layout (256B-aligned slices), ~4.4 MB total.
    char* w = (char*)d_ws;
    size_t off = 0;
    auto alloc = [&](size_t bytes) {
        char* p = w + off;
        off = (off + bytes + 255) & ~(size_t)255;
        return p;
    };
    int*   hcnt     = (int*)alloc((size_t)N * 4);
    int*   tcnt     = (int*)alloc((size_t)N * 4);
    int*   row_ptr  = (int*)alloc((size_t)(N + 1) * 4);
    int*   cursor   = (int*)alloc((size_t)N * 4);
    float* dis      = (float*)alloc((size_t)N * 4);
    int*   bsum     = (int*)alloc((size_t)nb * 4);
    int*   edge_src = (int*)alloc((size_t)E * 4);

    hipMemsetAsync(hcnt, 0, (size_t)N * 4, stream);
    hipMemsetAsync(tcnt, 0, (size_t)N * 4, stream);

    int eb = (E + 255) / 256;
    hist_kernel<<<eb, 256, 0, stream>>>(h, t, hcnt, tcnt, E);
    scan_block_kernel<<<nb, SCAN_BLK, 0, stream>>>(tcnt, row_ptr, bsum, N);
    scan_small_kernel<<<1, 256, 0, stream>>>(bsum, nb);
    finalize_kernel<<<(N + 255) / 256, 256, 0, stream>>>(row_ptr, bsum, cursor, hcnt, dis, N, E);
    place_kernel<<<eb, 256, 0, stream>>>(h, t, cursor, edge_src, E);

    long long total = (long long)N * 32;
    gather_kernel<<<(int)((total + 255) / 256), 256, 0, stream>>>(x, row_ptr, edge_src, dis, out, N);
}

// Round 3
// 142.418 us; speedup vs baseline: 7.4957x; 1.0559x over previous
//
#include <hip/hip_runtime.h>

#define D_FEAT 128
#define SCAN_BLK 1024

// Histogram of sources (deg for norm) and targets (CSR row counts).
__global__ void hist_kernel(const int* __restrict__ h, const int* __restrict__ t,
                            int* __restrict__ hcnt, int* __restrict__ tcnt, int E) {
    int i = blockIdx.x * blockDim.x + threadIdx.x;
    if (i < E) {
        atomicAdd(&hcnt[h[i]], 1);
        atomicAdd(&tcnt[t[i]], 1);
    }
}

// Per-block exclusive scan: shuffle-based wave scan + LDS wave-sum scan.
__global__ void scan_block_kernel(const int* __restrict__ in, int* __restrict__ out,
                                  int* __restrict__ bsum, int n) {
    int i = blockIdx.x * SCAN_BLK + threadIdx.x;
    int v = (i < n) ? in[i] : 0;
    int lane = threadIdx.x & 63;
    int wid = threadIdx.x >> 6;

    // inclusive scan within wave (64 lanes)
    int s = v;
    #pragma unroll
    for (int off = 1; off < 64; off <<= 1) {
        int u = __shfl_up(s, off, 64);
        if (lane >= off) s += u;
    }

    __shared__ int wsum[16];
    if (lane == 63) wsum[wid] = s;
    __syncthreads();
    if (threadIdx.x < 16) {
        int ws = wsum[threadIdx.x];
        #pragma unroll
        for (int off = 1; off < 16; off <<= 1) {
            int u = __shfl_up(ws, off, 16);
            if ((threadIdx.x & 15) >= off) ws += u;
        }
        wsum[threadIdx.x] = ws;  // inclusive wave-sum scan
    }
    __syncthreads();
    int base = (wid > 0) ? wsum[wid - 1] : 0;
    int incl = base + s;
    if (i < n) out[i] = incl - v;  // exclusive
    if (threadIdx.x == SCAN_BLK - 1) bsum[blockIdx.x] = incl;
}

// Fused: add block-sum prefix (reduced in-block), cursor copy, dis = deg^-1/2.
__global__ void finalize_kernel(int* __restrict__ row_ptr, const int* __restrict__ bsum,
                                int* __restrict__ cursor, const int* __restrict__ hcnt,
                                float* __restrict__ dis, int n, int E) {
    // all 256 nodes of this block live in scan-chunk blockIdx.x>>2 (256 | 1024)
    int chunk = blockIdx.x >> 2;
    int lane = threadIdx.x & 63;
    int wid = threadIdx.x >> 6;

    // prefix = sum of bsum[0..chunk-1]; chunk <= 97 < 256 threads
    int v = (threadIdx.x < chunk) ? bsum[threadIdx.x] : 0;
    #pragma unroll
    for (int off = 32; off > 0; off >>= 1) v += __shfl_down(v, off, 64);
    __shared__ int ws[4];
    if (lane == 0) ws[wid] = v;
    __syncthreads();
    __shared__ int prefix;
    if (threadIdx.x == 0) prefix = ws[0] + ws[1] + ws[2] + ws[3];
    __syncthreads();

    int i = blockIdx.x * blockDim.x + threadIdx.x;
    if (i < n) {
        int r = row_ptr[i] + prefix;
        row_ptr[i] = r;
        cursor[i] = r;
        dis[i] = rsqrtf((float)hcnt[i]);
    }
    if (i == 0) row_ptr[n] = E;
}

// Bucket edges by target: edge_src[pos] = h[e].
__global__ void place_kernel(const int* __restrict__ h, const int* __restrict__ t,
                             int* __restrict__ cursor, int* __restrict__ edge_src, int E) {
    int i = blockIdx.x * blockDim.x + threadIdx.x;
    if (i < E) {
        int pos = atomicAdd(&cursor[t[i]], 1);
        edge_src[pos] = h[i];
    }
}

// One 32-lane group per node; lane j owns float4 chunk j. 4x unrolled for MLP.
__global__ void gather_kernel(const float* __restrict__ x, const int* __restrict__ row_ptr,
                              const int* __restrict__ edge_src, const float* __restrict__ dis,
                              float* __restrict__ out, int n) {
    int gid = blockIdx.x * blockDim.x + threadIdx.x;
    int node = gid >> 5;
    int j = gid & 31;
    if (node >= n) return;
    int beg = row_ptr[node];
    int end = row_ptr[node + 1];
    const float4* x4 = reinterpret_cast<const float4*>(x);
    float4 acc = make_float4(0.f, 0.f, 0.f, 0.f);
    int k = beg;
    for (; k + 4 <= end; k += 4) {
        int s0 = edge_src[k + 0];
        int s1 = edge_src[k + 1];
        int s2 = edge_src[k + 2];
        int s3 = edge_src[k + 3];
        float n0 = dis[s0], n1 = dis[s1], n2 = dis[s2], n3 = dis[s3];
        float4 v0 = x4[(size_t)s0 * 32 + j];
        float4 v1 = x4[(size_t)s1 * 32 + j];
        float4 v2 = x4[(size_t)s2 * 32 + j];
        float4 v3 = x4[(size_t)s3 * 32 + j];
        acc.x = fmaf(n0, v0.x, acc.x); acc.y = fmaf(n0, v0.y, acc.y);
        acc.z = fmaf(n0, v0.z, acc.z); acc.w = fmaf(n0, v0.w, acc.w);
        acc.x = fmaf(n1, v1.x, acc.x); acc.y = fmaf(n1, v1.y, acc.y);
        acc.z = fmaf(n1, v1.z, acc.z); acc.w = fmaf(n1, v1.w, acc.w);
        acc.x = fmaf(n2, v2.x, acc.x); acc.y = fmaf(n2, v2.y, acc.y);
        acc.z = fmaf(n2, v2.z, acc.z); acc.w = fmaf(n2, v2.w, acc.w);
        acc.x = fmaf(n3, v3.x, acc.x); acc.y = fmaf(n3, v3.y, acc.y);
        acc.z = fmaf(n3, v3.z, acc.z); acc.w = fmaf(n3, v3.w, acc.w);
    }
    for (; k < end; ++k) {
        int s = edge_src[k];
        float nr = dis[s];
        float4 v = x4[(size_t)s * 32 + j];
        acc.x = fmaf(nr, v.x, acc.x); acc.y = fmaf(nr, v.y, acc.y);
        acc.z = fmaf(nr, v.z, acc.z); acc.w = fmaf(nr, v.w, acc.w);
    }
    float dd = dis[node];
    float4 r;
    r.x = fmaxf(dd * acc.x, 0.f);
    r.y = fmaxf(dd * acc.y, 0.f);
    r.z = fmaxf(dd * acc.z, 0.f);
    r.w = fmaxf(dd * acc.w, 0.f);
    reinterpret_cast<float4*>(out)[(size_t)node * 32 + j] = r;
}

extern "C" void kernel_launch(void* const* d_in, const int* in_sizes, int n_in,
                              void* d_out, int out_size, void* d_ws, size_t ws_size,
                              hipStream_t stream) {
    const float* x = (const float*)d_in[0];
    const int*   h = (const int*)d_in[1];
    const int*   t = (const int*)d_in[2];
    float* out = (float*)d_out;

    int N = in_sizes[0] / D_FEAT;   // 100000
    int E = in_sizes[1];            // 600000
    int nb = (N + SCAN_BLK - 1) / SCAN_BLK;  // 98 (<=256 assumed)

    char* w = (char*)d_ws;
    size_t off = 0;
    auto alloc = [&](size_t bytes) {
        char* p = w + off;
        off = (off + bytes + 255) & ~(size_t)255;
        return p;
    };
    int*   counts   = (int*)alloc((size_t)2 * N * 4);  // hcnt | tcnt contiguous
    int*   hcnt     = counts;
    int*   tcnt     = counts + N;
    int*   row_ptr  = (int*)alloc((size_t)(N + 1) * 4);
    int*   cursor   = (int*)alloc((size_t)N * 4);
    float* dis      = (float*)alloc((size_t)N * 4);
    int*   bsum     = (int*)alloc((size_t)nb * 4);
    int*   edge_src = (int*)alloc((size_t)E * 4);

    hipMemsetAsync(counts, 0, (size_t)2 * N * 4, stream);

    int eb = (E + 255) / 256;
    hist_kernel<<<eb, 256, 0, stream>>>(h, t, hcnt, tcnt, E);
    scan_block_kernel<<<nb, SCAN_BLK, 0, stream>>>(tcnt, row_ptr, bsum, N);
    finalize_kernel<<<(N + 255) / 256, 256, 0, stream>>>(row_ptr, bsum, cursor, hcnt, dis, N, E);
    place_kernel<<<eb, 256, 0, stream>>>(h, t, cursor, edge_src, E);

    long long total = (long long)N * 32;
    gather_kernel<<<(int)((total + 255) / 256), 256, 0, stream>>>(x, row_ptr, edge_src, dis, out, N);
}